// Round 17
// baseline (201.973 us; speedup 1.0000x reference)
//
#include <hip/hip_runtime.h>

#define NB    4096
#define TSTEP 256
#define DTC   0.01f

typedef _Float16 h8 __attribute__((ext_vector_type(8)));
typedef float    f4 __attribute__((ext_vector_type(4)));

// tanh(a) = (E-1)/(E+1), E=exp(2a); upper clamp only (exp2(-inf)->0 -> -1 cleanly)
__device__ __forceinline__ float fast_tanh(float a) {
    float t = fminf(a * 2.885390082f, 126.0f);
    float E = __builtin_amdgcn_exp2f(t);
    return (E - 1.0f) * __builtin_amdgcn_rcpf(E + 1.0f);
}
// exp(m) for |m| <= ~0.06: 3-term Taylor, rel err < 4e-7 (validated r13/r14, absmax 36)
__device__ __forceinline__ float texp(float m) {
    return fmaf(m, fmaf(m, fmaf(m, 1.0f/6.0f, 0.5f), 1.0f), 1.0f);
}
// stacked block-diagonal layer-2 weight in TRUE coordinates
__device__ __forceinline__ float W2v(const float* Wc2, const float* Wr2, int C, int U) {
    if (C < 48) return (U < 48) ? Wc2[C*48 + U] : 0.0f;
    return (U >= 48) ? Wr2[(C-48)*16 + (U-48)] : 0.0f;
}
// ordering idiom (r12-proven): LDS visibility without any vmcnt drain
__device__ __forceinline__ void lds_barrier() {
    asm volatile("s_waitcnt lgkmcnt(0)" ::: "memory");
    __builtin_amdgcn_s_barrier();
    asm volatile("" ::: "memory");
}

// Zero-exchange layout (per wave, 16 elems; lane = (e=lane&15, g=lane>>4)):
//  y true-feats at lane:   {12g..12g+11} (6 rot pairs) + {48+4g..+3} (4 r-modes)
//  L1 k-label   υ:  k=8g+i -> 12g+i ; k=32+8g+i -> i<4 ? 12g+8+i : 48+4g+(i-4)
//  u slot-label σ1: slot 16t+m -> 16*(m>>2)+4t+(m&3)   (lane's u-set = {16g..16g+15})
//  L2 k-label   τ:  k=8g+i -> 16g+i ; k=32+8g+i -> 16g+8+i   (== σ1 sets, no exchange)
//  c slot-label σ2: t<3: 12*(m>>2)+4t+(m&3) ; t=3: 48+4*(m>>2)+(m&3)
//  => rotation coeffs colocate with y pairs; r-modes = tile 3 (uniform, no branch)
__global__ void __launch_bounds__(64) __attribute__((amdgpu_waves_per_eu(1, 1)))
koopman_kernel(const float* __restrict__ x,
               const float* __restrict__ Wc1, const float* __restrict__ bc1,
               const float* __restrict__ Wc2, const float* __restrict__ bc2,
               const float* __restrict__ Wr1, const float* __restrict__ br1,
               const float* __restrict__ Wr2, const float* __restrict__ br2,
               float* __restrict__ out)
{
    const int lane = threadIdx.x & 63;
    const int e    = lane & 15;
    const int g    = lane >> 4;
    const int blk  = blockIdx.x;

    // store-staging buffer: element-major rows (68-float stride)
    __shared__ __align__(16) float ST[16 * 68];

    // ---- persistent A fragments with the double permutation baked in ----
    h8 a1lo[4], a1hi[4], a2lo[4], a2hi[4];
    #pragma unroll
    for (int t = 0; t < 4; ++t) {
        const int F1 = 16*(e>>2) + 4*t + (e&3);            // σ1 row
        const float* w1row = (F1 < 48) ? (Wc1 + F1*64) : (Wr1 + (F1-48)*64);
        #pragma unroll
        for (int i = 0; i < 8; ++i) a1lo[t][i] = (_Float16)w1row[12*g + i];
        #pragma unroll
        for (int i = 0; i < 8; ++i) {
            const int col = (i < 4) ? (12*g + 8 + i) : (48 + 4*g + (i-4));
            a1hi[t][i] = (_Float16)w1row[col];
        }
        const int C2 = (t < 3) ? (12*(e>>2) + 4*t + (e&3)) // σ2 row
                               : (48 + 4*(e>>2) + (e&3));
        #pragma unroll
        for (int i = 0; i < 8; ++i) a2lo[t][i] = (_Float16)W2v(Wc2, Wr2, C2, 16*g + i);
        #pragma unroll
        for (int i = 0; i < 8; ++i) a2hi[t][i] = (_Float16)W2v(Wc2, Wr2, C2, 16*g + 8 + i);
    }
    // biases in C/D layout (row 4g+r of tile t)
    f4 b1f[4], b2f[4];
    #pragma unroll
    for (int t = 0; t < 4; ++t) {
        #pragma unroll
        for (int r = 0; r < 4; ++r) {
            const int F = 16*g + 4*t + r;
            b1f[t][r] = (F < 48) ? bc1[F] : br1[F-48];
            const int C = (t < 3) ? (12*g + 4*t + r) : (48 + 4*g + r);
            b2f[t][r] = (C < 48) ? bc2[C] : br2[C-48];
        }
    }

    // ---- y state (f32) in B-fragment order ----
    const float* xp = x + (size_t)(blk*16 + e) * 64;
    float yv0[8], yv1[8];
    #pragma unroll
    for (int i = 0; i < 8; ++i) yv0[i] = xp[12*g + i];
    #pragma unroll
    for (int i = 0; i < 4; ++i) yv1[i] = xp[12*g + 8 + i];
    #pragma unroll
    for (int i = 0; i < 4; ++i) yv1[4+i] = xp[48 + 4*g + i];

    const int o0 = 12*g;           // 12 contiguous complex feats (ST row offset)
    const int o1 = 48 + 4*g;       // 4 contiguous real feats
    // r12-proven store shape: lane (e,g) stores feats [16j+4g, +4) of element e;
    // per instruction j, lanes {e, e+16, e+32, e+48} cover one contiguous 64B chunk
    float* gps = out + (size_t)(blk*16 + e) * (TSTEP*64) + 4*g;

    for (int t = 0; t < TSTEP; ++t) {
        // ---- pack y -> f16 B fragments (state stays f32) ----
        h8 by0, by1;
        #pragma unroll
        for (int i = 0; i < 8; ++i) { by0[i] = (_Float16)yv0[i]; by1[i] = (_Float16)yv1[i]; }

        // ---- layer 1 on matrix pipe: 4 tiles x 2 k-halves ----
        f4 acc1[4];
        #pragma unroll
        for (int q = 0; q < 4; ++q)
            acc1[q] = __builtin_amdgcn_mfma_f32_16x16x32_f16(a1lo[q], by0, b1f[q], 0, 0, 0);
        #pragma unroll
        for (int q = 0; q < 4; ++q)
            acc1[q] = __builtin_amdgcn_mfma_f32_16x16x32_f16(a1hi[q], by1, acc1[q], 0, 0, 0);

        // ---- tanh (16 values) -> f16 B fragments for layer 2 ----
        h8 bu0, bu1;
        #pragma unroll
        for (int j = 0; j < 8; ++j) bu0[j] = (_Float16)fast_tanh(acc1[j>>2][j&3]);
        #pragma unroll
        for (int j = 0; j < 8; ++j) bu1[j] = (_Float16)fast_tanh(acc1[2+(j>>2)][j&3]);

        // ---- layer 2 ----
        f4 acc2[4];
        #pragma unroll
        for (int q = 0; q < 4; ++q)
            acc2[q] = __builtin_amdgcn_mfma_f32_16x16x32_f16(a2lo[q], bu0, b2f[q], 0, 0, 0);
        #pragma unroll
        for (int q = 0; q < 4; ++q)
            acc2[q] = __builtin_amdgcn_mfma_f32_16x16x32_f16(a2hi[q], bu1, acc2[q], 0, 0, 0);

        // ---- pointwise: 6 rotation pairs (coeffs reg-local) + 4 decays (tile 3) ----
        #pragma unroll
        for (int p = 0; p < 6; ++p) {
            const float mu = acc2[p>>1][(2*p)&3];
            const float om = acc2[p>>1][(2*p+1)&3];
            const float E  = texp(DTC * mu);
            const float xx = DTC * om;
            const float q2 = xx * xx;
            float sp = fmaf(q2, 1.0f/120.0f, -1.0f/6.0f); sp = fmaf(q2, sp, 1.0f);
            float cp = fmaf(q2, 1.0f/24.0f,  -0.5f);      cp = fmaf(q2, cp, 1.0f);
            const float s = E * xx * sp;
            const float c = E * cp;
            float y0, y1;
            if (p < 4) { y0 = yv0[2*p];     y1 = yv0[2*p+1]; }
            else       { y0 = yv1[2*(p-4)]; y1 = yv1[2*(p-4)+1]; }
            const float n0 = fmaf(c, y0, -s * y1);
            const float n1 = fmaf(s, y0,  c * y1);
            if (p < 4) { yv0[2*p] = n0;     yv0[2*p+1] = n1; }
            else       { yv1[2*(p-4)] = n0; yv1[2*(p-4)+1] = n1; }
        }
        #pragma unroll
        for (int j = 0; j < 4; ++j) yv1[4+j] *= texp(DTC * acc2[3][j]);

        // ---- stage y rows in LDS, barrier, then drain ALL 4KB coalesced ----
        f4 s0 = {yv0[0], yv0[1], yv0[2], yv0[3]};
        f4 s1 = {yv0[4], yv0[5], yv0[6], yv0[7]};
        f4 s2 = {yv1[0], yv1[1], yv1[2], yv1[3]};
        f4 s3 = {yv1[4], yv1[5], yv1[6], yv1[7]};
        *reinterpret_cast<f4*>(&ST[e*68 + o0    ]) = s0;
        *reinterpret_cast<f4*>(&ST[e*68 + o0 + 4]) = s1;
        *reinterpret_cast<f4*>(&ST[e*68 + o0 + 8]) = s2;
        *reinterpret_cast<f4*>(&ST[e*68 + o1    ]) = s3;
        lds_barrier();                       // staging visible to all lanes

        #pragma unroll
        for (int j = 0; j < 4; ++j) {        // 4 instrs x 64 lanes x 16B = full 4KB
            const f4 sv = *reinterpret_cast<const f4*>(&ST[e*68 + 16*j + 4*g]);
            *reinterpret_cast<f4*>(gps + 16*j) = sv;
        }
        gps += 64;
        lds_barrier();                       // drain reads done before next overwrite
    }
}

extern "C" void kernel_launch(void* const* d_in, const int* in_sizes, int n_in,
                              void* d_out, int out_size, void* d_ws, size_t ws_size,
                              hipStream_t stream) {
    const float* x   = (const float*)d_in[0];
    const float* Wc1 = (const float*)d_in[1];
    const float* bc1 = (const float*)d_in[2];
    const float* Wc2 = (const float*)d_in[3];
    const float* bc2 = (const float*)d_in[4];
    const float* Wr1 = (const float*)d_in[5];
    const float* br1 = (const float*)d_in[6];
    const float* Wr2 = (const float*)d_in[7];
    const float* br2 = (const float*)d_in[8];
    float* out = (float*)d_out;

    koopman_kernel<<<dim3(NB / 16), dim3(64), 0, stream>>>(
        x, Wc1, bc1, Wc2, bc2, Wr1, br1, Wr2, br2, out);
}

// Round 18
// 154.898 us; speedup vs baseline: 1.3039x; 1.3039x over previous
//
#include <hip/hip_runtime.h>

#define NB    4096
#define TSTEP 256
#define DTC   0.01f

typedef _Float16 h8 __attribute__((ext_vector_type(8)));
typedef _Float16 h4 __attribute__((ext_vector_type(4)));
typedef float    f4 __attribute__((ext_vector_type(4)));

// tanh(a) = (E-1)/(E+1), E=exp(2a); upper clamp only (exp2(-inf)->0 -> -1 cleanly)
__device__ __forceinline__ float fast_tanh(float a) {
    float t = fminf(a * 2.885390082f, 126.0f);
    float E = __builtin_amdgcn_exp2f(t);
    return (E - 1.0f) * __builtin_amdgcn_rcpf(E + 1.0f);
}
// exp(m) for |m| <= ~0.06: 3-term Taylor, rel err < 4e-7 (validated r13/r14/r17)
__device__ __forceinline__ float texp(float m) {
    return fmaf(m, fmaf(m, fmaf(m, 1.0f/6.0f, 0.5f), 1.0f), 1.0f);
}
// stacked block-diagonal layer-2 weight in TRUE coordinates
__device__ __forceinline__ float W2v(const float* Wc2, const float* Wr2, int C, int U) {
    if (C < 48) return (U < 48) ? Wc2[C*48 + U] : 0.0f;
    return (U >= 48) ? Wr2[(C-48)*16 + (U-48)] : 0.0f;
}
// r12-proven ordering idiom: LDS visibility, NO vmcnt drain (stores stay async)
__device__ __forceinline__ void lds_barrier() {
    asm volatile("s_waitcnt lgkmcnt(0)" ::: "memory");
    __builtin_amdgcn_s_barrier();
    asm volatile("" ::: "memory");
}

// Structure: 1 block (256 thr, 4 waves) per CU; 16 elements per block.
// Every wave computes FULL layer-1 (8 MFMAs, redundant) + 16 tanh; the
// ψ-relabeling  ψ(32h+8g+i) = 16*(2h+(i>>2)) + 4g + (i&3)  makes each lane's
// 16 L1 outputs exactly its own L2 B-fragment (zero u-exchange). Each wave's
// L2 computes only its own 16-feat tile (σ2=identity ⇒ pointwise pairs are
// register-local; wave 3 = real modes). Only new-y crosses waves: f16
// ping-pong LDS buffer, ONE barrier per step. Stores: r12's exact pattern.
__global__ void __launch_bounds__(256) __attribute__((amdgpu_waves_per_eu(1, 1)))
koopman_kernel(const float* __restrict__ x,
               const float* __restrict__ Wc1, const float* __restrict__ bc1,
               const float* __restrict__ Wc2, const float* __restrict__ bc2,
               const float* __restrict__ Wr1, const float* __restrict__ br1,
               const float* __restrict__ Wr2, const float* __restrict__ br2,
               float* __restrict__ out)
{
    const int tid  = threadIdx.x;
    const int lane = tid & 63;
    const int w    = tid >> 6;          // wave id: owns feature tile [16w,16w+16) for L2
    const int e    = lane & 15;         // element column
    const int g    = lane >> 4;         // k-group / C-D row group
    const int blk  = blockIdx.x;

    // y broadcast, f16, double-buffered: [buf][elem][feat], feat-stride 72 f16
    __shared__ __align__(16) _Float16 Y[2][16 * 72];

    // ---- A1: full W1s (4 tiles x 2 k-halves), identity labeling ----
    h8 a1[4][2];
    #pragma unroll
    for (int q = 0; q < 4; ++q) {
        const int F = 16*q + e;
        const float* row1 = (F < 48) ? (Wc1 + F*64) : (Wr1 + (F-48)*64);
        #pragma unroll
        for (int h = 0; h < 2; ++h)
            #pragma unroll
            for (int i = 0; i < 8; ++i)
                a1[q][h][i] = (_Float16)row1[32*h + 8*g + i];
    }
    // ---- A2: own 16-row tile, columns labeled by ψ ----
    h8 a2[2];
    {
        const int C = 16*w + e;
        #pragma unroll
        for (int h = 0; h < 2; ++h)
            #pragma unroll
            for (int i = 0; i < 8; ++i) {
                const int U = 16*(2*h + (i >> 2)) + 4*g + (i & 3);
                a2[h][i] = (_Float16)W2v(Wc2, Wr2, C, U);
            }
    }
    // ---- biases (C/D layout) ----
    f4 b1f[4], b2f;
    #pragma unroll
    for (int q = 0; q < 4; ++q)
        #pragma unroll
        for (int r = 0; r < 4; ++r) {
            const int F = 16*q + 4*g + r;
            b1f[q][r] = (F < 48) ? bc1[F] : br1[F-48];
        }
    #pragma unroll
    for (int r = 0; r < 4; ++r) {
        const int C = 16*w + 4*g + r;
        b2f[r] = (C < 48) ? bc2[C] : br2[C-48];
    }

    // ---- state: this lane's 4 owned features of element e ----
    float ys[4];
    #pragma unroll
    for (int r = 0; r < 4; ++r)
        ys[r] = x[(size_t)(blk*16 + e)*64 + 16*w + 4*g + r];

    // ---- initial Y[0] fill: 16 rows x 64 feats via 256 threads x 4 feats ----
    {
        const int row = tid >> 4, col4 = (tid & 15) * 4;
        const f4 xv = *reinterpret_cast<const f4*>(x + (size_t)(blk*16 + row)*64 + col4);
        h4 p; p[0]=(_Float16)xv[0]; p[1]=(_Float16)xv[1]; p[2]=(_Float16)xv[2]; p[3]=(_Float16)xv[3];
        *reinterpret_cast<h4*>(&Y[0][row*72 + col4]) = p;
    }
    __syncthreads();

    const bool cwave = (w < 3);
    float* gps = out + (size_t)(blk*16 + e) * (TSTEP*64) + 16*w + 4*g;

    for (int t = 0; t < TSTEP; ++t) {
        // ---- read full y for element e (identity feat order) ----
        const _Float16* yb = &Y[t & 1][e * 72];
        const h8 by0 = *reinterpret_cast<const h8*>(yb + 8*g);        // feats 8g..8g+7
        const h8 by1 = *reinterpret_cast<const h8*>(yb + 32 + 8*g);   // feats 32+8g..

        // ---- full layer 1: 4 tiles x 2 k-halves (4 independent 2-chains) ----
        f4 acc1[4];
        #pragma unroll
        for (int q = 0; q < 4; ++q)
            acc1[q] = __builtin_amdgcn_mfma_f32_16x16x32_f16(a1[q][0], by0, b1f[q], 0, 0, 0);
        #pragma unroll
        for (int q = 0; q < 4; ++q)
            acc1[q] = __builtin_amdgcn_mfma_f32_16x16x32_f16(a1[q][1], by1, acc1[q], 0, 0, 0);

        // ---- tanh + ψ-pack: lane's 16 u values ARE its L2 B-fragment ----
        h8 bu0, bu1;
        #pragma unroll
        for (int i = 0; i < 8; ++i) bu0[i] = (_Float16)fast_tanh(acc1[(i >> 2)    ][i & 3]);
        #pragma unroll
        for (int i = 0; i < 8; ++i) bu1[i] = (_Float16)fast_tanh(acc1[2 + (i >> 2)][i & 3]);

        // ---- layer 2: own tile only (2 MFMAs) ----
        f4 acc2 = __builtin_amdgcn_mfma_f32_16x16x32_f16(a2[0], bu0, b2f, 0, 0, 0);
        acc2    = __builtin_amdgcn_mfma_f32_16x16x32_f16(a2[1], bu1, acc2, 0, 0, 0);

        // ---- pointwise: 2 register-local pairs (w<3) or 4 decays (w==3) ----
        if (cwave) {
            const float E0 = texp(DTC * acc2[0]);
            const float x0 = DTC * acc2[1];
            const float E1 = texp(DTC * acc2[2]);
            const float x1 = DTC * acc2[3];
            const float q0 = x0*x0, q1 = x1*x1;
            float sp0 = fmaf(q0, 1.0f/120.0f, -1.0f/6.0f); sp0 = fmaf(q0, sp0, 1.0f);
            float cp0 = fmaf(q0, 1.0f/24.0f,  -0.5f);      cp0 = fmaf(q0, cp0, 1.0f);
            float sp1 = fmaf(q1, 1.0f/120.0f, -1.0f/6.0f); sp1 = fmaf(q1, sp1, 1.0f);
            float cp1 = fmaf(q1, 1.0f/24.0f,  -0.5f);      cp1 = fmaf(q1, cp1, 1.0f);
            const float s0 = E0 * x0 * sp0, c0 = E0 * cp0;
            const float s1 = E1 * x1 * sp1, c1 = E1 * cp1;
            const float n0 = fmaf(c0, ys[0], -s0 * ys[1]);
            const float n1 = fmaf(s0, ys[0],  c0 * ys[1]);
            const float n2 = fmaf(c1, ys[2], -s1 * ys[3]);
            const float n3 = fmaf(s1, ys[2],  c1 * ys[3]);
            ys[0]=n0; ys[1]=n1; ys[2]=n2; ys[3]=n3;
        } else {
            ys[0] *= texp(DTC * acc2[0]);
            ys[1] *= texp(DTC * acc2[1]);
            ys[2] *= texp(DTC * acc2[2]);
            ys[3] *= texp(DTC * acc2[3]);
        }

        // ---- publish new y (f16) into the NEXT buffer; direct f32 store ----
        h4 yp;
        yp[0]=(_Float16)ys[0]; yp[1]=(_Float16)ys[1];
        yp[2]=(_Float16)ys[2]; yp[3]=(_Float16)ys[3];
        *reinterpret_cast<h4*>(&Y[(t + 1) & 1][e*72 + 16*w + 4*g]) = yp;

        const f4 sv = {ys[0], ys[1], ys[2], ys[3]};
        *reinterpret_cast<f4*>(gps) = sv;   // r12-proven exact store shape, async
        gps += 64;

        lds_barrier();                      // next-buffer writes visible; ONE sync/step
    }
}

extern "C" void kernel_launch(void* const* d_in, const int* in_sizes, int n_in,
                              void* d_out, int out_size, void* d_ws, size_t ws_size,
                              hipStream_t stream) {
    const float* x   = (const float*)d_in[0];
    const float* Wc1 = (const float*)d_in[1];
    const float* bc1 = (const float*)d_in[2];
    const float* Wc2 = (const float*)d_in[3];
    const float* bc2 = (const float*)d_in[4];
    const float* Wr1 = (const float*)d_in[5];
    const float* br1 = (const float*)d_in[6];
    const float* Wr2 = (const float*)d_in[7];
    const float* br2 = (const float*)d_in[8];
    float* out = (float*)d_out;

    koopman_kernel<<<dim3(NB / 16), dim3(256), 0, stream>>>(
        x, Wc1, bc1, Wc2, bc2, Wr1, br1, Wr2, br2, out);
}

// Round 19
// 124.738 us; speedup vs baseline: 1.6192x; 1.2418x over previous
//
#include <hip/hip_runtime.h>

#define NB    4096
#define TSTEP 256
#define EPB   16      // batch elements per block (= MFMA N)
#define DTC   0.01f

typedef _Float16 h8 __attribute__((ext_vector_type(8)));
typedef _Float16 h4 __attribute__((ext_vector_type(4)));
typedef float    f4 __attribute__((ext_vector_type(4)));

// tanh(a) = (E-1)/(E+1), E=exp(2a); upper clamp only (exp2(-inf)->0 -> -1 cleanly)
__device__ __forceinline__ float fast_tanh(float a) {
    float t = fminf(a * 2.885390082f, 126.0f);
    float E = __builtin_amdgcn_exp2f(t);
    return (E - 1.0f) * __builtin_amdgcn_rcpf(E + 1.0f);
}
// exp(m) for |m| <= ~0.06 (inputs bounded by tanh): 3-term Taylor, rel err < 4e-7
__device__ __forceinline__ float texp(float m) {
    return fmaf(m, fmaf(m, fmaf(m, 1.0f/6.0f, 0.5f), 1.0f), 1.0f);
}

// raw workgroup barrier: LDS visibility only, NO vmcnt drain (stores stay async)
__device__ __forceinline__ void lds_barrier() {
    asm volatile("s_waitcnt lgkmcnt(0)" ::: "memory");
    __builtin_amdgcn_s_barrier();
    asm volatile("" ::: "memory");
}

// LDS map (bytes): y16 f16[16][72] @0 (2304) | u16 f16[16][72] @2304  -- 4608 total
#define U16B  2304

__global__ void __launch_bounds__(256)
koopman_kernel(const float* __restrict__ x,
               const float* __restrict__ Wc1, const float* __restrict__ bc1,
               const float* __restrict__ Wc2, const float* __restrict__ bc2,
               const float* __restrict__ Wr1, const float* __restrict__ br1,
               const float* __restrict__ Wr2, const float* __restrict__ br2,
               float* __restrict__ out)
{
    const int tid  = threadIdx.x;
    const int lane = tid & 63;
    const int w    = tid >> 6;          // wave id: owns feature tile [16w, 16w+16)
    const int blk  = blockIdx.x;

    __shared__ __align__(16) unsigned char L[U16B * 2];

    const int e = lane & 15;            // elem column (B/D col, A row-within-tile)
    const int g = lane >> 4;            // k-group

    // ---- persistent A fragments (f16 weights): 16 VGPRs total ----
    const int fa = 16*w + e;            // this lane's A row (feature)
    h8 a1lo, a1hi, a2lo, a2hi;
    {
        const float* r1 = (fa < 48) ? (Wc1 + fa*64) : (Wr1 + (fa-48)*64);
        #pragma unroll
        for (int i = 0; i < 8; ++i) {
            a1lo[i] = (_Float16)r1[8*g + i];
            a1hi[i] = (_Float16)r1[32 + 8*g + i];
        }
        #pragma unroll
        for (int i = 0; i < 8; ++i) {   // stacked block-diag layer 2 (64x64, zero-padded)
            const int k0 = 8*g + i, k1 = k0 + 32;
            float v0, v1;
            if (fa < 48) {
                v0 = (k0 < 48) ? Wc2[fa*48 + k0] : 0.0f;
                v1 = (k1 < 48) ? Wc2[fa*48 + k1] : 0.0f;
            } else {
                v0 = (k0 >= 48) ? Wr2[(fa-48)*16 + (k0-48)] : 0.0f;
                v1 = (k1 >= 48) ? Wr2[(fa-48)*16 + (k1-48)] : 0.0f;
            }
            a2lo[i] = (_Float16)v0;
            a2hi[i] = (_Float16)v1;
        }
    }
    // biases + y state in C/D layout: feat = 16w + 4g + r, elem = e
    f4 b1v, b2v;
    float ys[4];
    #pragma unroll
    for (int r = 0; r < 4; ++r) {
        const int f = 16*w + 4*g + r;
        b1v[r] = (f < 48) ? bc1[f] : br1[f-48];
        b2v[r] = (f < 48) ? bc2[f] : br2[f-48];
        ys[r]  = x[(blk*EPB + e)*64 + f];
    }
    const bool cwave = (w < 3);         // waves 0-2: complex pairs; wave 3: real modes

    // ---- loop-invariant addresses ----
    const int rdoff = e*144 + 16*g;                 // B-frag b128 read
    const int wroff = e*144 + (16*w + 4*g)*2;       // f16 b64 write
    // direct register store: lane (e,g) owns 16B of elem e's 256B row (r12-exact)
    float* gp = out + (size_t)(blk*EPB + e) * (TSTEP*64) + 16*w + 4*g;

    // ---- initial y16 fill: 16 rows x 64 feats via 256 threads x 4 feats ----
    {
        const int row = tid >> 4, col4 = (tid & 15) * 4;
        const f4 xv = *reinterpret_cast<const f4*>(x + (blk*EPB + row)*64 + col4);
        h4 p; p[0]=(_Float16)xv[0]; p[1]=(_Float16)xv[1]; p[2]=(_Float16)xv[2]; p[3]=(_Float16)xv[3];
        *reinterpret_cast<h4*>(L + row*144 + col4*2) = p;
    }
    __syncthreads();

    for (int t = 0; t < TSTEP; ++t) {
        // ---- phase 1: u = tanh(W1s @ y + b1); independent MFMAs, then add ----
        const h8 by0 = *reinterpret_cast<const h8*>(L + rdoff);
        const h8 by1 = *reinterpret_cast<const h8*>(L + rdoff + 64);
        f4 aL = b1v;
        f4 aH = {0.0f, 0.0f, 0.0f, 0.0f};
        aL = __builtin_amdgcn_mfma_f32_16x16x32_f16(a1lo, by0, aL, 0, 0, 0);
        aH = __builtin_amdgcn_mfma_f32_16x16x32_f16(a1hi, by1, aH, 0, 0, 0);
        const f4 a = aL + aH;
        h4 up;
        up[0]=(_Float16)fast_tanh(a[0]); up[1]=(_Float16)fast_tanh(a[1]);
        up[2]=(_Float16)fast_tanh(a[2]); up[3]=(_Float16)fast_tanh(a[3]);
        *reinterpret_cast<h4*>(L + U16B + wroff) = up;
        lds_barrier();

        // ---- phase 2: co/re = W2s @ u + b2 ----
        const h8 bu0 = *reinterpret_cast<const h8*>(L + U16B + rdoff);
        const h8 bu1 = *reinterpret_cast<const h8*>(L + U16B + rdoff + 64);
        f4 cL = b2v;
        f4 cH = {0.0f, 0.0f, 0.0f, 0.0f};
        cL = __builtin_amdgcn_mfma_f32_16x16x32_f16(a2lo, bu0, cL, 0, 0, 0);
        cH = __builtin_amdgcn_mfma_f32_16x16x32_f16(a2hi, bu1, cH, 0, 0, 0);
        const f4 c = cL + cH;

        // ---- pointwise: Taylor exp/sin/cos (|dt*c| <= ~0.055, bounded by tanh) ----
        if (cwave) {
            const float m0 = DTC * c[0], x0 = DTC * c[1];
            const float m1 = DTC * c[2], x1 = DTC * c[3];
            const float E0 = texp(m0), E1 = texp(m1);
            const float q0 = x0*x0, q1 = x1*x1;
            float sp0 = fmaf(q0, 1.0f/120.0f, -1.0f/6.0f); sp0 = fmaf(q0, sp0, 1.0f);
            float cp0 = fmaf(q0, 1.0f/24.0f,  -0.5f);      cp0 = fmaf(q0, cp0, 1.0f);
            float sp1 = fmaf(q1, 1.0f/120.0f, -1.0f/6.0f); sp1 = fmaf(q1, sp1, 1.0f);
            float cp1 = fmaf(q1, 1.0f/24.0f,  -0.5f);      cp1 = fmaf(q1, cp1, 1.0f);
            const float s0 = E0 * x0 * sp0, c0v = E0 * cp0;
            const float s1 = E1 * x1 * sp1, c1v = E1 * cp1;
            const float n0 = fmaf(c0v, ys[0], -s0 * ys[1]);
            const float n1 = fmaf(s0,  ys[0],  c0v * ys[1]);
            const float n2 = fmaf(c1v, ys[2], -s1 * ys[3]);
            const float n3 = fmaf(s1,  ys[2],  c1v * ys[3]);
            ys[0]=n0; ys[1]=n1; ys[2]=n2; ys[3]=n3;
        } else {
            ys[0] *= texp(DTC * c[0]);
            ys[1] *= texp(DTC * c[1]);
            ys[2] *= texp(DTC * c[2]);
            ys[3] *= texp(DTC * c[3]);
        }

        // ---- publish y (f16 for next matmul) + async direct f32 store ----
        h4 yp;
        yp[0]=(_Float16)ys[0]; yp[1]=(_Float16)ys[1]; yp[2]=(_Float16)ys[2]; yp[3]=(_Float16)ys[3];
        *reinterpret_cast<h4*>(L + wroff) = yp;
        f4 yv = {ys[0], ys[1], ys[2], ys[3]};
        *reinterpret_cast<f4*>(gp) = yv;    // never drained in-loop (raw barriers)
        gp += 64;
        lds_barrier();
    }
}

extern "C" void kernel_launch(void* const* d_in, const int* in_sizes, int n_in,
                              void* d_out, int out_size, void* d_ws, size_t ws_size,
                              hipStream_t stream) {
    const float* x   = (const float*)d_in[0];
    const float* Wc1 = (const float*)d_in[1];
    const float* bc1 = (const float*)d_in[2];
    const float* Wc2 = (const float*)d_in[3];
    const float* bc2 = (const float*)d_in[4];
    const float* Wr1 = (const float*)d_in[5];
    const float* br1 = (const float*)d_in[6];
    const float* Wr2 = (const float*)d_in[7];
    const float* br2 = (const float*)d_in[8];
    float* out = (float*)d_out;

    koopman_kernel<<<dim3(NB / EPB), dim3(256), 0, stream>>>(
        x, Wc1, bc1, Wc2, bc2, Wr1, br1, Wr2, br2, out);
}

// Round 20
// 122.468 us; speedup vs baseline: 1.6492x; 1.0185x over previous
//
#include <hip/hip_runtime.h>

#define NB    4096
#define TSTEP 256
#define EPB   16      // batch elements per block (= MFMA N)
#define DTC   0.01f

typedef _Float16 h8 __attribute__((ext_vector_type(8)));
typedef _Float16 h4 __attribute__((ext_vector_type(4)));
typedef float    f4 __attribute__((ext_vector_type(4)));

#define KE  0.014426950409f   // dt * log2(e)
#define REV 1.59154943e-3f    // dt / (2*pi)  (v_sin/v_cos take revolutions)

// tanh(a) = (E-1)/(E+1), E=exp(2a); upper clamp only (exp2(-inf)->0 -> -1 cleanly)
__device__ __forceinline__ float fast_tanh(float a) {
    float t = fminf(a * 2.885390082f, 126.0f);
    float E = __builtin_amdgcn_exp2f(t);
    return (E - 1.0f) * __builtin_amdgcn_rcpf(E + 1.0f);
}

// raw workgroup barrier: LDS visibility only, NO vmcnt drain (stores stay async)
__device__ __forceinline__ void lds_barrier() {
    asm volatile("s_waitcnt lgkmcnt(0)" ::: "memory");
    __builtin_amdgcn_s_barrier();
    asm volatile("" ::: "memory");
}

// LDS map (bytes): y16 f16[16][72] @0 (2304) | u16 f16[16][72] @2304  -- 4608 total
#define U16B  2304

__global__ void __launch_bounds__(256)
koopman_kernel(const float* __restrict__ x,
               const float* __restrict__ Wc1, const float* __restrict__ bc1,
               const float* __restrict__ Wc2, const float* __restrict__ bc2,
               const float* __restrict__ Wr1, const float* __restrict__ br1,
               const float* __restrict__ Wr2, const float* __restrict__ br2,
               float* __restrict__ out)
{
    const int tid  = threadIdx.x;
    const int lane = tid & 63;
    const int w    = tid >> 6;          // wave id: owns feature tile [16w, 16w+16)
    const int blk  = blockIdx.x;

    __shared__ __align__(16) unsigned char L[U16B * 2];

    const int e = lane & 15;            // elem column (B/D col, A row-within-tile)
    const int g = lane >> 4;            // k-group

    // ---- persistent A fragments (f16 weights): 16 VGPRs total ----
    const int fa = 16*w + e;            // this lane's A row (feature)
    h8 a1lo, a1hi, a2lo, a2hi;
    {
        const float* r1 = (fa < 48) ? (Wc1 + fa*64) : (Wr1 + (fa-48)*64);
        #pragma unroll
        for (int i = 0; i < 8; ++i) {
            a1lo[i] = (_Float16)r1[8*g + i];
            a1hi[i] = (_Float16)r1[32 + 8*g + i];
        }
        #pragma unroll
        for (int i = 0; i < 8; ++i) {   // stacked block-diag layer 2 (64x64, zero-padded)
            const int k0 = 8*g + i, k1 = k0 + 32;
            float v0, v1;
            if (fa < 48) {
                v0 = (k0 < 48) ? Wc2[fa*48 + k0] : 0.0f;
                v1 = (k1 < 48) ? Wc2[fa*48 + k1] : 0.0f;
            } else {
                v0 = (k0 >= 48) ? Wr2[(fa-48)*16 + (k0-48)] : 0.0f;
                v1 = (k1 >= 48) ? Wr2[(fa-48)*16 + (k1-48)] : 0.0f;
            }
            a2lo[i] = (_Float16)v0;
            a2hi[i] = (_Float16)v1;
        }
    }
    // biases + y state in C/D layout: feat = 16w + 4g + r, elem = e
    float b1v[4], b2v[4], ys[4];
    #pragma unroll
    for (int r = 0; r < 4; ++r) {
        const int f = 16*w + 4*g + r;
        b1v[r] = (f < 48) ? bc1[f] : br1[f-48];
        b2v[r] = (f < 48) ? bc2[f] : br2[f-48];
        ys[r]  = x[(blk*EPB + e)*64 + f];
    }
    const bool cwave = (w < 3);         // waves 0-2: complex pairs; wave 3: real modes

    // ---- loop-invariant addresses ----
    const int rdoff = e*144 + 16*g;                 // B-frag b128 read
    const int wroff = e*144 + (16*w + 4*g)*2;       // f16 b64 write
    // direct register store: lane (e,g) owns 16B of elem e's 256B row
    float* gp = out + (size_t)(blk*EPB + e) * (TSTEP*64) + 16*w + 4*g;

    // ---- initial y16 fill: 16 rows x 64 feats via 256 threads x 4 feats ----
    {
        const int row = tid >> 4, col4 = (tid & 15) * 4;
        const f4 xv = *reinterpret_cast<const f4*>(x + (blk*EPB + row)*64 + col4);
        h4 p; p[0]=(_Float16)xv[0]; p[1]=(_Float16)xv[1]; p[2]=(_Float16)xv[2]; p[3]=(_Float16)xv[3];
        *reinterpret_cast<h4*>(L + row*144 + col4*2) = p;
    }
    __syncthreads();

    for (int t = 0; t < TSTEP; ++t) {
        // ---- phase 1: u = tanh(W1s @ y + b1); independent MFMAs, then add ----
        const h8 by0 = *reinterpret_cast<const h8*>(L + rdoff);
        const h8 by1 = *reinterpret_cast<const h8*>(L + rdoff + 64);
        f4 aL = {b1v[0], b1v[1], b1v[2], b1v[3]};
        f4 aH = {0.0f, 0.0f, 0.0f, 0.0f};
        aL = __builtin_amdgcn_mfma_f32_16x16x32_f16(a1lo, by0, aL, 0, 0, 0);
        aH = __builtin_amdgcn_mfma_f32_16x16x32_f16(a1hi, by1, aH, 0, 0, 0);
        const f4 a = aL + aH;
        h4 up;
        up[0]=(_Float16)fast_tanh(a[0]); up[1]=(_Float16)fast_tanh(a[1]);
        up[2]=(_Float16)fast_tanh(a[2]); up[3]=(_Float16)fast_tanh(a[3]);
        *reinterpret_cast<h4*>(L + U16B + wroff) = up;
        lds_barrier();

        // ---- phase 2: co/re = W2s @ u + b2 ----
        const h8 bu0 = *reinterpret_cast<const h8*>(L + U16B + rdoff);
        const h8 bu1 = *reinterpret_cast<const h8*>(L + U16B + rdoff + 64);
        f4 cL = {b2v[0], b2v[1], b2v[2], b2v[3]};
        f4 cH = {0.0f, 0.0f, 0.0f, 0.0f};
        cL = __builtin_amdgcn_mfma_f32_16x16x32_f16(a2lo, bu0, cL, 0, 0, 0);
        cH = __builtin_amdgcn_mfma_f32_16x16x32_f16(a2hi, bu1, cH, 0, 0, 0);
        const f4 c = cL + cH;

        // ---- pointwise: pairs register-local, role wave-uniform ----
        if (cwave) {
            const float sc0 = __builtin_amdgcn_exp2f(KE * c[0]);
            const float sc1 = __builtin_amdgcn_exp2f(KE * c[2]);
            const float s0 = __builtin_amdgcn_sinf(REV * c[1]) * sc0;
            const float c0 = __builtin_amdgcn_cosf(REV * c[1]) * sc0;
            const float s1 = __builtin_amdgcn_sinf(REV * c[3]) * sc1;
            const float c1 = __builtin_amdgcn_cosf(REV * c[3]) * sc1;
            const float n0 = c0*ys[0] - s0*ys[1];
            const float n1 = s0*ys[0] + c0*ys[1];
            const float n2 = c1*ys[2] - s1*ys[3];
            const float n3 = s1*ys[2] + c1*ys[3];
            ys[0]=n0; ys[1]=n1; ys[2]=n2; ys[3]=n3;
        } else {
            ys[0] *= __builtin_amdgcn_exp2f(KE * c[0]);
            ys[1] *= __builtin_amdgcn_exp2f(KE * c[1]);
            ys[2] *= __builtin_amdgcn_exp2f(KE * c[2]);
            ys[3] *= __builtin_amdgcn_exp2f(KE * c[3]);
        }

        // ---- publish y (f16 for next matmul) + async direct f32 store ----
        h4 yp;
        yp[0]=(_Float16)ys[0]; yp[1]=(_Float16)ys[1]; yp[2]=(_Float16)ys[2]; yp[3]=(_Float16)ys[3];
        *reinterpret_cast<h4*>(L + wroff) = yp;
        f4 yv = {ys[0], ys[1], ys[2], ys[3]};
        *reinterpret_cast<f4*>(gp) = yv;    // never drained in-loop (raw barriers)
        gp += 64;
        lds_barrier();
    }
}

extern "C" void kernel_launch(void* const* d_in, const int* in_sizes, int n_in,
                              void* d_out, int out_size, void* d_ws, size_t ws_size,
                              hipStream_t stream) {
    const float* x   = (const float*)d_in[0];
    const float* Wc1 = (const float*)d_in[1];
    const float* bc1 = (const float*)d_in[2];
    const float* Wc2 = (const float*)d_in[3];
    const float* bc2 = (const float*)d_in[4];
    const float* Wr1 = (const float*)d_in[5];
    const float* br1 = (const float*)d_in[6];
    const float* Wr2 = (const float*)d_in[7];
    const float* br2 = (const float*)d_in[8];
    float* out = (float*)d_out;

    koopman_kernel<<<dim3(NB / EPB), dim3(256), 0, stream>>>(
        x, Wc1, bc1, Wc2, bc2, Wr1, br1, Wr2, br2, out);
}